// Round 20
// baseline (156.909 us; speedup 1.0000x reference)
//
#include <hip/hip_runtime.h>
#include <math.h>

#define Ddim 384
#define D4 96
#define NUM_ITEMS 16384
#define NUM_CLUSTERS 256
#define NEG_INF_F (-1e9f)
#define NTOK 4096
#define NFILLB 2048                // fill blocks (D1)
#define NGB 256                    // gemm blocks (D2)
#define RSTRIDE 97                 // member-row LDS stride (float4)
#define KP 68                      // padded k-row length in floats

__device__ __forceinline__ float dot4(const float4& a, const float4& b) {
    return a.x * b.x + a.y * b.y + a.z * b.z + a.w * b.w;
}

// ---------- D1: pure fill (solo on device -> rocclr-class BW) ----------
__global__ __launch_bounds__(256) void hs_fill(float* __restrict__ dummy_out)
{
    const size_t base = (size_t)blockIdx.x * 256 + threadIdx.x;
    float4 z; z.x = z.y = z.z = z.w = 0.f;
    float4* o4 = reinterpret_cast<float4*>(dummy_out) + base;
    #pragma unroll 8
    for (int i = 0; i < 32; ++i)
        o4[(size_t)i * (NFILLB * 256)] = z;
}

// ---------- D2: cluster GEMM (256 blocks) + meta (block 256) ----------
// GEMM tile 64 tokens x 64 clusters, k-chunks of 32, double-buffered LDS,
// 4x4 micro-tile/lane. Total traffic: h 6MB + CE 24MB, writes clg 4MB into
// dummy_out[0..4MB) (re-zeroed in D4). No fill mixed in -> no stream clash.
__global__ __launch_bounds__(256, 2) void hs_gemm(
    const float* __restrict__ hidden,
    const float* __restrict__ cluster_emb,
    const int*   __restrict__ targets,
    const int*   __restrict__ cluster_assign,
    float* __restrict__ dummy_out,
    int*   __restrict__ wsI)
{
    const int bid = blockIdx.x;
    const int tid = threadIdx.x;

    __shared__ float hS[2][32][KP];
    __shared__ float cS[2][32][KP];
    __shared__ int   cnt[NUM_CLUSTERS], scan[NUM_CLUSTERS], cur[NUM_CLUSTERS];

    if (bid == NGB) {
        // ---- meta: bucket tokens by target cluster ----
        cnt[tid] = 0; cur[tid] = 0;
        __syncthreads();
        int tcv[NTOK / 256];
        #pragma unroll
        for (int i = 0; i < NTOK / 256; ++i) {
            const int t = i * 256 + tid;
            const int tc = cluster_assign[targets[t]];
            tcv[i] = tc;
            atomicAdd(&cnt[tc], 1);
        }
        __syncthreads();
        scan[tid] = cnt[tid];
        __syncthreads();
        for (int d = 1; d < 256; d <<= 1) {
            const int v = (tid >= d) ? scan[tid - d] : 0;
            __syncthreads();
            scan[tid] += v;
            __syncthreads();
        }
        wsI[tid] = scan[tid] - cnt[tid];
        if (tid == 255) wsI[256] = NTOK;
        __syncthreads();
        #pragma unroll
        for (int i = 0; i < NTOK / 256; ++i) {
            const int t = i * 256 + tid;
            const int tc = tcv[i];
            const int p = atomicAdd(&cur[tc], 1);
            wsI[257 + (scan[tc] - cnt[tc]) + p] = t;
        }
        return;
    }

    const int g  = bid;                // 0..255
    const int t0 = (g & 63) * 64;
    const int c0 = (g >> 6) * 64;
    const int ty = tid >> 4;
    const int tx = tid & 15;

    const float4* hg = reinterpret_cast<const float4*>(hidden);
    const float4* cg = reinterpret_cast<const float4*>(cluster_emb);
    const int srow0 = tid >> 3, sc8 = tid & 7;

    float acc[4][4];
    #pragma unroll
    for (int i = 0; i < 4; ++i)
        #pragma unroll
        for (int j = 0; j < 4; ++j) acc[i][j] = 0.f;

    float4 rh[2], rc[2];
    #pragma unroll
    for (int ph = 0; ph < 2; ++ph) {
        const int row = srow0 + ph * 32;
        rh[ph] = hg[(size_t)(t0 + row) * D4 + sc8];
        rc[ph] = cg[(size_t)(c0 + row) * D4 + sc8];
    }
    int cb = 0;
    #pragma unroll
    for (int ph = 0; ph < 2; ++ph) {
        const int row = srow0 + ph * 32;
        const int kl = sc8 * 4;
        hS[0][kl+0][row] = rh[ph].x; hS[0][kl+1][row] = rh[ph].y;
        hS[0][kl+2][row] = rh[ph].z; hS[0][kl+3][row] = rh[ph].w;
        cS[0][kl+0][row] = rc[ph].x; cS[0][kl+1][row] = rc[ph].y;
        cS[0][kl+2][row] = rc[ph].z; cS[0][kl+3][row] = rc[ph].w;
    }
    __syncthreads();

    for (int kk = 0; kk < 12; ++kk) {
        if (kk < 11) {
            #pragma unroll
            for (int ph = 0; ph < 2; ++ph) {
                const int row = srow0 + ph * 32;
                rh[ph] = hg[(size_t)(t0 + row) * D4 + (kk + 1) * 8 + sc8];
                rc[ph] = cg[(size_t)(c0 + row) * D4 + (kk + 1) * 8 + sc8];
            }
        }
        #pragma unroll
        for (int k = 0; k < 32; ++k) {
            const float4 hv = *reinterpret_cast<const float4*>(&hS[cb][k][ty * 4]);
            const float4 cv = *reinterpret_cast<const float4*>(&cS[cb][k][tx * 4]);
            acc[0][0] += hv.x * cv.x; acc[0][1] += hv.x * cv.y;
            acc[0][2] += hv.x * cv.z; acc[0][3] += hv.x * cv.w;
            acc[1][0] += hv.y * cv.x; acc[1][1] += hv.y * cv.y;
            acc[1][2] += hv.y * cv.z; acc[1][3] += hv.y * cv.w;
            acc[2][0] += hv.z * cv.x; acc[2][1] += hv.z * cv.y;
            acc[2][2] += hv.z * cv.z; acc[2][3] += hv.z * cv.w;
            acc[3][0] += hv.w * cv.x; acc[3][1] += hv.w * cv.y;
            acc[3][2] += hv.w * cv.z; acc[3][3] += hv.w * cv.w;
        }
        if (kk < 11) {
            const int nb = cb ^ 1;
            #pragma unroll
            for (int ph = 0; ph < 2; ++ph) {
                const int row = srow0 + ph * 32;
                const int kl = sc8 * 4;
                hS[nb][kl+0][row] = rh[ph].x; hS[nb][kl+1][row] = rh[ph].y;
                hS[nb][kl+2][row] = rh[ph].z; hS[nb][kl+3][row] = rh[ph].w;
                cS[nb][kl+0][row] = rc[ph].x; cS[nb][kl+1][row] = rc[ph].y;
                cS[nb][kl+2][row] = rc[ph].z; cS[nb][kl+3][row] = rc[ph].w;
            }
            __syncthreads();
            cb = nb;
        }
    }

    float* clg = dummy_out;
    #pragma unroll
    for (int i = 0; i < 4; ++i) {
        float4 v; v.x = acc[i][0]; v.y = acc[i][1]; v.z = acc[i][2]; v.w = acc[i][3];
        *reinterpret_cast<float4*>(
            &clg[(size_t)(t0 + ty * 4 + i) * NUM_CLUSTERS + c0 + tx * 4]) = v;
    }
}

// ---------- D3: member (bucketed) + cluster softmax, mixed grid ----------
__global__ __launch_bounds__(256) void hs_phase2(
    const float* __restrict__ hidden,
    const float* __restrict__ item_emb,
    const float* __restrict__ item_mask,
    const int*   __restrict__ targets,
    const int*   __restrict__ cluster_assign,
    const int*   __restrict__ in_cluster_id,
    const float* __restrict__ clg,
    const int*   __restrict__ wsI,
    float* __restrict__ ws)
{
    const int bid  = blockIdx.x;
    const int tid  = threadIdx.x;
    const int lane = tid & 63;
    const int wid  = tid >> 6;

    __shared__ float4 rows[64 * RSTRIDE];

    if (bid & 1) {
        // ---- softmax: 16 tokens, 4 per wave ----
        const int t0 = (bid >> 1) * 16;
        #pragma unroll
        for (int p = 0; p < 4; ++p) {
            const int gt = t0 + wid * 4 + p;
            const float* row = clg + (size_t)gt * NUM_CLUSTERS;
            const float v0 = row[lane];
            const float v1 = row[lane + 64];
            const float v2 = row[lane + 128];
            const float v3 = row[lane + 192];
            float bv = v0; int bi = lane;
            if (v1 > bv) { bv = v1; bi = lane + 64;  }
            if (v2 > bv) { bv = v2; bi = lane + 128; }
            if (v3 > bv) { bv = v3; bi = lane + 192; }
            #pragma unroll
            for (int m = 32; m > 0; m >>= 1) {
                const float ov = __shfl_xor(bv, m);
                const int   oi = __shfl_xor(bi, m);
                if (ov > bv || (ov == bv && oi < bi)) { bv = ov; bi = oi; }
            }
            float e = expf(v0 - bv) + expf(v1 - bv) + expf(v2 - bv) + expf(v3 - bv);
            #pragma unroll
            for (int m = 32; m > 0; m >>= 1) e += __shfl_xor(e, m);
            const float lse = bv + logf(e);
            if (lane == 0) {
                const int tc = cluster_assign[targets[gt]];
                ws[NTOK + gt]     = item_mask[gt];
                ws[2 * NTOK + gt] = row[tc] - lse;
                ws[4 * NTOK + gt] = (bi == tc) ? 1.f : 0.f;
            }
        }
        return;
    }

    const int c    = bid >> 1;
    const int off  = wsI[c];
    const int cntc = wsI[c + 1] - off;
    if (cntc == 0) return;

    const float4* ie4 = reinterpret_cast<const float4*>(item_emb);
    for (int j = tid; j < 64 * D4; j += 256) {
        const int s = j / D4, col = j % D4;
        const int id = c + (s << 8);            // arithmetic member id, s < 64
        rows[s * RSTRIDE + (col ^ ((s >> 3) & 7))] = ie4[(size_t)id * D4 + col];
    }
    __syncthreads();

    const int  swz  = (lane >> 3) & 7;
    const int* list = wsI + 257;

    for (int i = wid * 2; i < cntc; i += 8) {
        const int tokA  = __builtin_amdgcn_readfirstlane(list[off + i]);
        const bool hasB = (i + 1) < cntc;
        const int tokB  = hasB ? __builtin_amdgcn_readfirstlane(list[off + i + 1]) : tokA;
        const float4* hA = reinterpret_cast<const float4*>(hidden + (size_t)tokA * Ddim);
        const float4* hB = reinterpret_cast<const float4*>(hidden + (size_t)tokB * Ddim);
        float mA = 0.f, mB = 0.f;
        #pragma unroll 8
        for (int k = 0; k < D4; ++k) {
            const float4 rv = rows[lane * RSTRIDE + (k ^ swz)];
            mA += dot4(rv, hA[k]);
            mB += dot4(rv, hB[k]);
        }
        float mxA = mA, mxB = mB;
        #pragma unroll
        for (int m = 32; m > 0; m >>= 1) {
            mxA = fmaxf(mxA, __shfl_xor(mxA, m));
            mxB = fmaxf(mxB, __shfl_xor(mxB, m));
        }
        float eA = expf(mA - mxA);
        float eB = expf(mB - mxB);
        #pragma unroll
        for (int m = 32; m > 0; m >>= 1) {
            eA += __shfl_xor(eA, m);
            eB += __shfl_xor(eB, m);
        }
        const int tpA = in_cluster_id[targets[tokA]];
        const int tpB = in_cluster_id[targets[tokB]];
        const float vA = __shfl(mA, tpA);
        const float vB = __shfl(mB, tpB);
        if (lane == 0) {
            ws[3 * NTOK + tokA] = vA - (mxA + logf(eA));
            if (hasB) ws[3 * NTOK + tokB] = vB - (mxB + logf(eB));
        }
    }
}

// ---------- D4: re-zero clg region (4MB) + final reduce ----------
__global__ __launch_bounds__(256) void hs_tail(
    const float* __restrict__ ws, float* __restrict__ dummy_out,
    float* __restrict__ out)
{
    const int bid = blockIdx.x;
    const int tid = threadIdx.x;

    if (bid < 8) {
        float4 z; z.x = z.y = z.z = z.w = 0.f;
        float4* o4 = reinterpret_cast<float4*>(dummy_out)
                     + (size_t)bid * 256 + tid;
        #pragma unroll 8
        for (int i = 0; i < 128; ++i)
            o4[(size_t)i * 2048] = z;      // covers float4 [0, 262144)
        return;
    }

    __shared__ double red[5][256];
    double a0 = 0, a1 = 0, a2 = 0, a3 = 0, a4 = 0;
    for (int i = tid; i < NTOK; i += 256) {
        const float msk  = ws[NTOK + i];
        const float tlpc = ws[2 * NTOK + i];
        const float tlpi = ws[3 * NTOK + i];
        a0 += (double)(-(tlpc + tlpi) * msk);
        a1 += (double)msk;
        a2 += (double)tlpc;
        a3 += (double)tlpi;
        a4 += (double)ws[4 * NTOK + i];
    }
    red[0][tid] = a0; red[1][tid] = a1; red[2][tid] = a2;
    red[3][tid] = a3; red[4][tid] = a4;
    __syncthreads();
    for (int s2 = 128; s2 > 0; s2 >>= 1) {
        if (tid < s2) {
            red[0][tid] += red[0][tid + s2];
            red[1][tid] += red[1][tid + s2];
            red[2][tid] += red[2][tid + s2];
            red[3][tid] += red[3][tid + s2];
            red[4][tid] += red[4][tid + s2];
        }
        __syncthreads();
    }
    if (tid == 0) {
        out[0] = (float)(red[0][0] / (red[1][0] + 1e-8));
        out[1] = (float)(-red[2][0] / (double)NTOK);
        out[2] = (float)(-red[3][0] / (double)NTOK);
        out[3] = (float)(red[4][0] / (double)NTOK);
    }
}

extern "C" void kernel_launch(void* const* d_in, const int* in_sizes, int n_in,
                              void* d_out, int out_size, void* d_ws, size_t ws_size,
                              hipStream_t stream) {
    const float* hidden         = (const float*)d_in[0];
    const float* item_emb       = (const float*)d_in[1];
    const float* cluster_emb    = (const float*)d_in[2];
    const float* item_mask      = (const float*)d_in[3];
    const int*   targets        = (const int*)d_in[4];
    const int*   cluster_assign = (const int*)d_in[5];
    const int*   in_cluster_id  = (const int*)d_in[7];

    float* out = (float*)d_out;
    float* ws  = (float*)d_ws;
    int*   wsI = (int*)(ws + 5 * NTOK);

    const size_t dummy_elems = (size_t)NTOK * NUM_ITEMS; // 67,108,864 zeros

    // Fully segregated phases: fill alone, then traffic-minimal compute.
    hs_fill<<<NFILLB, 256, 0, stream>>>(out);
    hs_gemm<<<NGB + 1, 256, 0, stream>>>(
        hidden, cluster_emb, targets, cluster_assign, out, wsI);
    hs_phase2<<<2 * NUM_CLUSTERS, 256, 0, stream>>>(
        hidden, item_emb, item_mask, targets, cluster_assign,
        in_cluster_id, out, wsI, ws);
    hs_tail<<<9, 256, 0, stream>>>(ws, out, out + dummy_elems);
}

// Round 21
// 150.492 us; speedup vs baseline: 1.0426x; 1.0426x over previous
//
#include <hip/hip_runtime.h>
#include <math.h>

#define Ddim 384
#define D4 96
#define NUM_ITEMS 16384
#define NUM_CLUSTERS 256
#define NEG_INF_F (-1e9f)
#define NTOK 4096
#define TPB 16                     // tokens per cluster block
#define NFILLB 2048                // fill blocks (D1)
#define RSTRIDE 97                 // member-row LDS stride (float4)

__device__ __forceinline__ float dot4(const float4& a, const float4& b) {
    return a.x * b.x + a.y * b.y + a.z * b.z + a.w * b.w;
}
__device__ __forceinline__ void pin4(float4& v) {
    asm volatile("" : "+v"(v.x), "+v"(v.y), "+v"(v.z), "+v"(v.w));
}

// ---------- D1: pure fill (2048 blocks) + meta (block 2048) ----------
// Fill and meta touch disjoint buffers -> safe in one grid; meta hides under fill.
__global__ __launch_bounds__(256) void hs_fill_meta(
    const int* __restrict__ targets, const int* __restrict__ cluster_assign,
    float* __restrict__ dummy_out, int* __restrict__ wsI)
{
    const int tid = threadIdx.x;

    if (blockIdx.x == NFILLB) {
        // ---- meta: bucket tokens by target cluster ----
        __shared__ int cnt[NUM_CLUSTERS], scan[NUM_CLUSTERS], cur[NUM_CLUSTERS];
        cnt[tid] = 0; cur[tid] = 0;
        __syncthreads();
        int tcv[NTOK / 256];
        #pragma unroll
        for (int i = 0; i < NTOK / 256; ++i) {
            const int t = i * 256 + tid;
            const int tc = cluster_assign[targets[t]];
            tcv[i] = tc;
            atomicAdd(&cnt[tc], 1);
        }
        __syncthreads();
        scan[tid] = cnt[tid];
        __syncthreads();
        for (int d = 1; d < 256; d <<= 1) {
            const int v = (tid >= d) ? scan[tid - d] : 0;
            __syncthreads();
            scan[tid] += v;
            __syncthreads();
        }
        wsI[tid] = scan[tid] - cnt[tid];
        if (tid == 255) wsI[256] = NTOK;
        __syncthreads();
        #pragma unroll
        for (int i = 0; i < NTOK / 256; ++i) {
            const int t = i * 256 + tid;
            const int tc = tcv[i];
            const int p = atomicAdd(&cur[tc], 1);
            wsI[257 + (scan[tc] - cnt[tc]) + p] = t;
        }
        return;
    }

    // ---- fill: grid-strided, R19 verbatim ----
    const size_t base = (size_t)blockIdx.x * 256 + tid;
    float4 z; z.x = z.y = z.z = z.w = 0.f;
    float4* o4 = reinterpret_cast<float4*>(dummy_out) + base;
    #pragma unroll 8
    for (int i = 0; i < 32; ++i)
        o4[(size_t)i * (NFILLB * 256)] = z;
}

// ---------- D2: member bucketed (256 blocks x 256 thr, all blocks alike) ----------
// item_emb read once (25 MB coalesced) instead of 402 MB scattered per-token.
__global__ __launch_bounds__(256) void hs_member(
    const float* __restrict__ hidden,
    const float* __restrict__ item_emb,
    const int*   __restrict__ targets,
    const int*   __restrict__ in_cluster_id,
    const int*   __restrict__ wsI,
    float* __restrict__ ws)
{
    const int c    = blockIdx.x;
    const int tid  = threadIdx.x;
    const int lane = tid & 63;
    const int wid  = tid >> 6;

    __shared__ float4 rows[64 * RSTRIDE];   // 99.3 KB, XOR-swizzled

    const int off  = wsI[c];
    const int cntc = wsI[c + 1] - off;
    if (cntc == 0) return;

    const float4* ie4 = reinterpret_cast<const float4*>(item_emb);
    for (int j = tid; j < 64 * D4; j += 256) {
        const int s = j / D4, col = j % D4;
        const int id = c + (s << 8);            // arithmetic member id, s < 64
        rows[s * RSTRIDE + (col ^ ((s >> 3) & 7))] = ie4[(size_t)id * D4 + col];
    }
    __syncthreads();

    const int  swz  = (lane >> 3) & 7;
    const int* list = wsI + 257;

    for (int i = wid * 2; i < cntc; i += 8) {
        const int tokA  = __builtin_amdgcn_readfirstlane(list[off + i]);
        const bool hasB = (i + 1) < cntc;
        const int tokB  = hasB ? __builtin_amdgcn_readfirstlane(list[off + i + 1]) : tokA;
        const float4* hA = reinterpret_cast<const float4*>(hidden + (size_t)tokA * Ddim);
        const float4* hB = reinterpret_cast<const float4*>(hidden + (size_t)tokB * Ddim);
        float mA = 0.f, mB = 0.f;
        #pragma unroll 8
        for (int k = 0; k < D4; ++k) {
            const float4 rv = rows[lane * RSTRIDE + (k ^ swz)];
            mA += dot4(rv, hA[k]);
            mB += dot4(rv, hB[k]);
        }
        float mxA = mA, mxB = mB;
        #pragma unroll
        for (int m = 32; m > 0; m >>= 1) {
            mxA = fmaxf(mxA, __shfl_xor(mxA, m));
            mxB = fmaxf(mxB, __shfl_xor(mxB, m));
        }
        float eA = expf(mA - mxA);
        float eB = expf(mB - mxB);
        #pragma unroll
        for (int m = 32; m > 0; m >>= 1) {
            eA += __shfl_xor(eA, m);
            eB += __shfl_xor(eB, m);
        }
        const int tpA = in_cluster_id[targets[tokA]];
        const int tpB = in_cluster_id[targets[tokB]];
        const float vA = __shfl(mA, tpA);
        const float vB = __shfl(mB, tpB);
        if (lane == 0) {
            ws[3 * NTOK + tokA] = vA - (mxA + logf(eA));
            if (hasB) ws[3 * NTOK + tokB] = vB - (mxB + logf(eB));
        }
    }
}

// ---------- D3: cluster with LDS-staged CE (R15's verified path, solo) ----------
// 256 blocks x 256 thr, 64 KB LDS -> 2 blocks/CU. CE global traffic 98 MB;
// dots fed from LDS instead of the L2 request path.
__global__ __launch_bounds__(256, 2) void hs_cluster(
    const float* __restrict__ hidden,
    const float* __restrict__ cluster_emb,
    const float* __restrict__ item_mask,
    const int*   __restrict__ targets,
    const int*   __restrict__ cluster_assign,
    float* __restrict__ ws)
{
    const int cb   = blockIdx.x;          // 0..255
    const int tid  = threadIdx.x;
    const int t0   = cb * TPB;
    const int lane = tid & 63;
    const int wid  = tid >> 6;            // 0..3
    const int q    = lane >> 4;           // 4-cluster subgroup
    const int r    = lane & 15;           // 16-lane D-split

    __shared__ float4 ce_lds[32 * D4];          // 48 KB: chunk of 32 clusters
    __shared__ float  clog[TPB][NUM_CLUSTERS];  // 16 KB

    const int tw = t0 + wid * 4;
    const float4* h4 = reinterpret_cast<const float4*>(hidden);
    float4 hf[4][6];
    #pragma unroll
    for (int j = 0; j < 4; ++j)
        #pragma unroll
        for (int i = 0; i < 6; ++i) {
            hf[j][i] = h4[(size_t)(tw + j) * D4 + i * 16 + r];
            pin4(hf[j][i]);
        }

    const float4* ce4 = reinterpret_cast<const float4*>(cluster_emb);
    for (int ch = 0; ch < 8; ++ch) {
        __syncthreads();
        #pragma unroll
        for (int jj = 0; jj < 12; ++jj)
            ce_lds[jj * 256 + tid] = ce4[ch * 3072 + jj * 256 + tid];
        __syncthreads();

        #pragma unroll 2
        for (int it = 0; it < 8; ++it) {
            const int cl = it * 4 + q;                  // 0..31 within chunk
            float4 ce[6];
            #pragma unroll
            for (int i = 0; i < 6; ++i) ce[i] = ce_lds[cl * D4 + i * 16 + r];
            float a0 = 0.f, a1 = 0.f, a2 = 0.f, a3 = 0.f;
            #pragma unroll
            for (int i = 0; i < 6; ++i) {
                a0 += dot4(ce[i], hf[0][i]);
                a1 += dot4(ce[i], hf[1][i]);
                a2 += dot4(ce[i], hf[2][i]);
                a3 += dot4(ce[i], hf[3][i]);
            }
            // fold 4 accumulators over 16 lanes: 5 shuffles total
            const bool hi8 = (r & 8) != 0;
            float u  = hi8 ? a1 : a0;
            float uS = hi8 ? a0 : a1;
            u += __shfl_xor(uS, 8);
            float w  = hi8 ? a3 : a2;
            float wS = hi8 ? a2 : a3;
            w += __shfl_xor(wS, 8);
            const bool hi4 = (r & 4) != 0;
            float zv = hi4 ? w : u;
            float zS = hi4 ? u : w;
            zv += __shfl_xor(zS, 4);
            zv += __shfl_xor(zv, 2);
            zv += __shfl_xor(zv, 1);
            if ((r & 3) == 0) {
                const int m = (r >> 2) & 3;             // class -> token {0,2,1,3}
                const int tokj = (m == 1) ? 2 : (m == 2) ? 1 : m;
                clog[wid * 4 + tokj][ch * 32 + cl] = zv;
            }
        }
    }
    __syncthreads();

    // ---- wave-local softmax + argmax (first-index tiebreak), 4 tokens/wave ----
    #pragma unroll
    for (int p = 0; p < 4; ++p) {
        const int t  = wid * 4 + p;
        const int gt = t0 + t;
        const float v0 = clog[t][lane];
        const float v1 = clog[t][lane + 64];
        const float v2 = clog[t][lane + 128];
        const float v3 = clog[t][lane + 192];
        float bv = v0; int bi = lane;
        if (v1 > bv) { bv = v1; bi = lane + 64;  }
        if (v2 > bv) { bv = v2; bi = lane + 128; }
        if (v3 > bv) { bv = v3; bi = lane + 192; }
        #pragma unroll
        for (int m = 32; m > 0; m >>= 1) {
            const float ov = __shfl_xor(bv, m);
            const int   oi = __shfl_xor(bi, m);
            if (ov > bv || (ov == bv && oi < bi)) { bv = ov; bi = oi; }
        }
        float e = expf(v0 - bv) + expf(v1 - bv) + expf(v2 - bv) + expf(v3 - bv);
        #pragma unroll
        for (int m = 32; m > 0; m >>= 1) e += __shfl_xor(e, m);
        const float lse = bv + logf(e);
        if (lane == 0) {
            const int tc = cluster_assign[targets[gt]];
            ws[NTOK + gt]     = item_mask[gt];
            ws[2 * NTOK + gt] = clog[t][tc] - lse;
            ws[4 * NTOK + gt] = (bi == tc) ? 1.f : 0.f;
        }
    }
}

// ---------- D4: deterministic final reduction ----------
__global__ __launch_bounds__(1024) void hs_final(
    const float* __restrict__ ws, float* __restrict__ out)
{
    __shared__ double red[5][1024];
    const int tid = threadIdx.x;
    double a0 = 0, a1 = 0, a2 = 0, a3 = 0, a4 = 0;
    for (int i = tid; i < NTOK; i += 1024) {
        const float msk  = ws[NTOK + i];
        const float tlpc = ws[2 * NTOK + i];
        const float tlpi = ws[3 * NTOK + i];
        a0 += (double)(-(tlpc + tlpi) * msk);
        a1 += (double)msk;
        a2 += (double)tlpc;
        a3 += (double)tlpi;
        a4 += (double)ws[4 * NTOK + i];
    }
    red[0][tid] = a0; red[1][tid] = a1; red[2][tid] = a2;
    red[3][tid] = a3; red[4][tid] = a4;
    __syncthreads();
    for (int s2 = 512; s2 > 0; s2 >>= 1) {
        if (tid < s2) {
            red[0][tid] += red[0][tid + s2];
            red[1][tid] += red[1][tid + s2];
            red[2][tid] += red[2][tid + s2];
            red[3][tid] += red[3][tid + s2];
            red[4][tid] += red[4][tid + s2];
        }
        __syncthreads();
    }
    if (tid == 0) {
        out[0] = (float)(red[0][0] / (red[1][0] + 1e-8));
        out[1] = (float)(-red[2][0] / (double)NTOK);
        out[2] = (float)(-red[3][0] / (double)NTOK);
        out[3] = (float)(red[4][0] / (double)NTOK);
    }
}

extern "C" void kernel_launch(void* const* d_in, const int* in_sizes, int n_in,
                              void* d_out, int out_size, void* d_ws, size_t ws_size,
                              hipStream_t stream) {
    const float* hidden         = (const float*)d_in[0];
    const float* item_emb       = (const float*)d_in[1];
    const float* cluster_emb    = (const float*)d_in[2];
    const float* item_mask      = (const float*)d_in[3];
    const int*   targets        = (const int*)d_in[4];
    const int*   cluster_assign = (const int*)d_in[5];
    const int*   in_cluster_id  = (const int*)d_in[7];

    float* out = (float*)d_out;
    float* ws  = (float*)d_ws;
    int*   wsI = (int*)(ws + 5 * NTOK);

    const size_t dummy_elems = (size_t)NTOK * NUM_ITEMS; // 67,108,864 zeros

    hs_fill_meta<<<NFILLB + 1, 256, 0, stream>>>(
        targets, cluster_assign, out, wsI);
    hs_member<<<NUM_CLUSTERS, 256, 0, stream>>>(
        hidden, item_emb, targets, in_cluster_id, wsI, ws);
    hs_cluster<<<NUM_CLUSTERS, 256, 0, stream>>>(
        hidden, cluster_emb, item_mask, targets, cluster_assign, ws);
    hs_final<<<1, 1024, 0, stream>>>(ws, out + dummy_elems);
}

// Round 22
// 116.933 us; speedup vs baseline: 1.3419x; 1.2870x over previous
//
#include <hip/hip_runtime.h>
#include <math.h>

#define Ddim 384
#define D4 96                      // Ddim/4
#define NUM_ITEMS 16384
#define NUM_CLUSTERS 256
#define MCS 128                    // MAX_CLUSTER_SIZE
#define NEG_INF_F (-1e9f)
#define NTOK 4096
#define TPB 8                      // tokens per compute block
#define NCB (NTOK / TPB)           // 512 compute blocks
#define NFILLB 2048                // fill blocks

__device__ __forceinline__ float dot4(const float4& a, const float4& b) {
    return a.x * b.x + a.y * b.y + a.z * b.z + a.w * b.w;
}

// ---------- D1: pure fill (R19 verbatim; solo on device) ----------
__global__ __launch_bounds__(256) void hs_fill(float* __restrict__ dummy_out)
{
    const size_t base = (size_t)blockIdx.x * 256 + threadIdx.x;
    float4 z; z.x = z.y = z.z = z.w = 0.f;
    float4* o4 = reinterpret_cast<float4*>(dummy_out) + base;
    #pragma unroll 8
    for (int i = 0; i < 32; ++i)
        o4[(size_t)i * (NFILLB * 256)] = z;
}

// ---------- D2: compute, 512 blocks x 512 thr (4096 waves = 4/SIMD) ----------
// R19's structure with the cluster phase split 4-ways: wave (wq, wquarter)
// computes 4 tokens x 64 clusters (same per-wave code, 16 iters instead of
// 32). Total CE traffic unchanged; wave count doubles -> 2x latency hiding.
// Each wave then finishes ONE token (softmax + member gather).
__global__ __launch_bounds__(512, 2) void hs_compute(
    const float* __restrict__ hidden,
    const float* __restrict__ item_emb,
    const float* __restrict__ cluster_emb,
    const float* __restrict__ item_mask,
    const int*   __restrict__ targets,
    const int*   __restrict__ cluster_assign,
    const int*   __restrict__ cluster_idx,
    const int*   __restrict__ in_cluster_id,
    float* __restrict__ ws)
{
    const int cb   = blockIdx.x;           // 0..511
    const int tid  = threadIdx.x;
    const int t0   = cb * TPB;
    const int lane = tid & 63;
    const int wave = tid >> 6;             // 0..7
    const int wq   = wave & 1;             // token quad (tokens wq*4..+3)
    const int wqt  = wave >> 1;            // 64-cluster quarter 0..3
    const int q    = lane >> 4;            // cluster subgroup 0..3
    const int r    = lane & 15;            // 16-lane D-split

    __shared__ float clog[TPB][NUM_CLUSTERS];   // 8 KB
    __shared__ float mlog[TPB][64];             // 2 KB

    // ---- cluster logits: wave covers 64 clusters x 4 tokens ----
    const int tw = t0 + wq * 4;
    const float4* h4 = reinterpret_cast<const float4*>(hidden);
    float4 hf[4][6];
    #pragma unroll
    for (int j = 0; j < 4; ++j)
        #pragma unroll
        for (int i = 0; i < 6; ++i)
            hf[j][i] = h4[(size_t)(tw + j) * D4 + i * 16 + r];

    const float4* ce4 = reinterpret_cast<const float4*>(cluster_emb);
    #pragma unroll 2
    for (int it = 0; it < 16; ++it) {
        const int c = wqt * 64 + it * 4 + q;
        float4 ce[6];
        #pragma unroll
        for (int i = 0; i < 6; ++i) ce[i] = ce4[(size_t)c * D4 + i * 16 + r];
        float a0 = 0.f, a1 = 0.f, a2 = 0.f, a3 = 0.f;
        #pragma unroll
        for (int i = 0; i < 6; ++i) {
            a0 += dot4(ce[i], hf[0][i]);
            a1 += dot4(ce[i], hf[1][i]);
            a2 += dot4(ce[i], hf[2][i]);
            a3 += dot4(ce[i], hf[3][i]);
        }
        // fold 4 accumulators over 16 lanes: 5 shuffles total (R19 verbatim)
        const bool hi8 = (r & 8) != 0;
        float u  = hi8 ? a1 : a0;
        float uS = hi8 ? a0 : a1;
        u += __shfl_xor(uS, 8);
        float w  = hi8 ? a3 : a2;
        float wS = hi8 ? a2 : a3;
        w += __shfl_xor(wS, 8);
        const bool hi4 = (r & 4) != 0;
        float zv = hi4 ? w : u;
        float zS = hi4 ? u : w;
        zv += __shfl_xor(zS, 4);
        zv += __shfl_xor(zv, 2);
        zv += __shfl_xor(zv, 1);
        if ((r & 3) == 0) {
            const int m = (r >> 2) & 3;               // class -> token {0,2,1,3}
            const int tokj = (m == 1) ? 2 : (m == 2) ? 1 : m;
            clog[wq * 4 + tokj][c] = zv;
        }
    }
    __syncthreads();   // four quarter-waves fill each token's clog row

    // ---- per wave: finish ONE token (softmax + member) ----
    const int r8 = lane & 7;
    const int g8 = lane >> 3;
    const float4* ie4 = reinterpret_cast<const float4*>(item_emb);

    const int t  = wave;
    const int gt = t0 + t;
    const int tgt  = targets[gt];
    const int tc   = cluster_assign[tgt];
    const int tpos = in_cluster_id[tgt];
    const float msk = item_mask[gt];

    // cluster softmax + argmax (first-index tiebreak)
    const float v0 = clog[t][lane];
    const float v1 = clog[t][lane + 64];
    const float v2 = clog[t][lane + 128];
    const float v3 = clog[t][lane + 192];
    float bv = v0; int bi = lane;
    if (v1 > bv) { bv = v1; bi = lane + 64;  }
    if (v2 > bv) { bv = v2; bi = lane + 128; }
    if (v3 > bv) { bv = v3; bi = lane + 192; }
    #pragma unroll
    for (int m = 32; m > 0; m >>= 1) {
        const float ov = __shfl_xor(bv, m);
        const int   oi = __shfl_xor(bi, m);
        if (ov > bv || (ov == bv && oi < bi)) { bv = ov; bi = oi; }
    }
    float e = expf(v0 - bv) + expf(v1 - bv) + expf(v2 - bv) + expf(v3 - bv);
    #pragma unroll
    for (int m = 32; m > 0; m >>= 1) e += __shfl_xor(e, m);
    const float lse = bv + logf(e);
    const float tlpc = clog[t][tc] - lse;

    // ---- member: 8-lane groups, 8 rows in flight, 64 valid slots ----
    float4 hme[12];
    #pragma unroll
    for (int i = 0; i < 12; ++i)
        hme[i] = h4[(size_t)gt * D4 + i * 8 + r8];
    const int* crow = cluster_idx + (size_t)tc * MCS;
    #pragma unroll 2
    for (int it = 0; it < 8; ++it) {
        const int id = crow[it * 8 + g8];   // always >= 0 for slot < 64
        const float4* ir = ie4 + (size_t)id * D4;
        float pa = 0.f;
        #pragma unroll
        for (int i = 0; i < 12; ++i) pa += dot4(ir[i * 8 + r8], hme[i]);
        pa += __shfl_xor(pa, 1);
        pa += __shfl_xor(pa, 2);
        pa += __shfl_xor(pa, 4);
        if (r8 == 0) mlog[t][it * 8 + g8] = pa;
    }
    // wave-local softmax over 64 slots (exact: slots 64..127 are masked)
    const float w0 = mlog[t][lane];
    float mx = w0;
    #pragma unroll
    for (int m = 32; m > 0; m >>= 1) mx = fmaxf(mx, __shfl_xor(mx, m));
    float e2 = expf(w0 - mx);
    #pragma unroll
    for (int m = 32; m > 0; m >>= 1) e2 += __shfl_xor(e2, m);
    const float tlpi = mlog[t][tpos] - (mx + logf(e2));

    if (lane == 0) {
        ws[NTOK + gt]     = msk;
        ws[2 * NTOK + gt] = tlpc;
        ws[3 * NTOK + gt] = tlpi;
        ws[4 * NTOK + gt] = (bi == tc) ? 1.f : 0.f;
    }
}

// ---------- D3: deterministic final reduction ----------
__global__ __launch_bounds__(1024) void hs_final(
    const float* __restrict__ ws, float* __restrict__ out)
{
    __shared__ double red[5][1024];
    const int tid = threadIdx.x;
    double a0 = 0, a1 = 0, a2 = 0, a3 = 0, a4 = 0;
    for (int i = tid; i < NTOK; i += 1024) {
        const float msk  = ws[NTOK + i];
        const float tlpc = ws[2 * NTOK + i];
        const float tlpi = ws[3 * NTOK + i];
        a0 += (double)(-(tlpc + tlpi) * msk);
        a1 += (double)msk;
        a2 += (double)tlpc;
        a3 += (double)tlpi;
        a4 += (double)ws[4 * NTOK + i];
    }
    red[0][tid] = a0; red[1][tid] = a1; red[2][tid] = a2;
    red[3][tid] = a3; red[4][tid] = a4;
    __syncthreads();
    for (int s2 = 512; s2 > 0; s2 >>= 1) {
        if (tid < s2) {
            red[0][tid] += red[0][tid + s2];
            red[1][tid] += red[1][tid + s2];
            red[2][tid] += red[2][tid + s2];
            red[3][tid] += red[3][tid + s2];
            red[4][tid] += red[4][tid + s2];
        }
        __syncthreads();
    }
    if (tid == 0) {
        out[0] = (float)(red[0][0] / (red[1][0] + 1e-8));
        out[1] = (float)(-red[2][0] / (double)NTOK);
        out[2] = (float)(-red[3][0] / (double)NTOK);
        out[3] = (float)(red[4][0] / (double)NTOK);
    }
}

extern "C" void kernel_launch(void* const* d_in, const int* in_sizes, int n_in,
                              void* d_out, int out_size, void* d_ws, size_t ws_size,
                              hipStream_t stream) {
    const float* hidden         = (const float*)d_in[0];
    const float* item_emb       = (const float*)d_in[1];
    const float* cluster_emb    = (const float*)d_in[2];
    const float* item_mask      = (const float*)d_in[3];
    const int*   targets        = (const int*)d_in[4];
    const int*   cluster_assign = (const int*)d_in[5];
    const int*   cluster_idx    = (const int*)d_in[6];
    const int*   in_cluster_id  = (const int*)d_in[7];

    float* out = (float*)d_out;
    float* ws  = (float*)d_ws;

    const size_t dummy_elems = (size_t)NTOK * NUM_ITEMS; // 67,108,864 zeros

    hs_fill<<<NFILLB, 256, 0, stream>>>(out);
    hs_compute<<<NCB, 512, 0, stream>>>(
        hidden, item_emb, cluster_emb, item_mask, targets,
        cluster_assign, cluster_idx, in_cluster_id, ws);
    hs_final<<<1, 1024, 0, stream>>>(ws, out + dummy_elems);
}

// Round 23
// 108.423 us; speedup vs baseline: 1.4472x; 1.0785x over previous
//
#include <hip/hip_runtime.h>
#include <math.h>

#define Ddim 384
#define D4 96                      // Ddim/4
#define NUM_ITEMS 16384
#define NUM_CLUSTERS 256
#define MCS 128                    // MAX_CLUSTER_SIZE
#define NEG_INF_F (-1e9f)
#define NTOK 4096
#define TPB 8                      // tokens per compute block
#define NCB (NTOK / TPB)           // 512 compute blocks
#define NFILLB 2048                // fill blocks

__device__ __forceinline__ float dot4(const float4& a, const float4& b) {
    return a.x * b.x + a.y * b.y + a.z * b.z + a.w * b.w;
}

// ---------- D1: pure fill (2048 blocks) + meta (block 2048) ----------
// Disjoint buffers -> safe in one grid; meta (~5us) hides under the fill.
__global__ __launch_bounds__(256) void hs_fill_meta(
    const int* __restrict__ targets, const int* __restrict__ cluster_assign,
    float* __restrict__ dummy_out, int* __restrict__ wsI)
{
    const int tid = threadIdx.x;

    if (blockIdx.x == NFILLB) {
        __shared__ int cnt[NUM_CLUSTERS], scan[NUM_CLUSTERS], cur[NUM_CLUSTERS];
        cnt[tid] = 0; cur[tid] = 0;
        __syncthreads();
        int tcv[NTOK / 256];
        #pragma unroll
        for (int i = 0; i < NTOK / 256; ++i) {
            const int t = i * 256 + tid;
            const int tc = cluster_assign[targets[t]];
            tcv[i] = tc;
            atomicAdd(&cnt[tc], 1);
        }
        __syncthreads();
        scan[tid] = cnt[tid];
        __syncthreads();
        for (int d = 1; d < 256; d <<= 1) {
            const int v = (tid >= d) ? scan[tid - d] : 0;
            __syncthreads();
            scan[tid] += v;
            __syncthreads();
        }
        wsI[tid] = scan[tid] - cnt[tid];
        if (tid == 255) wsI[256] = NTOK;
        __syncthreads();
        #pragma unroll
        for (int i = 0; i < NTOK / 256; ++i) {
            const int t = i * 256 + tid;
            const int tc = tcv[i];
            const int p = atomicAdd(&cur[tc], 1);
            wsI[257 + (scan[tc] - cnt[tc]) + p] = t;
        }
        return;
    }

    const size_t base = (size_t)blockIdx.x * 256 + tid;
    float4 z; z.x = z.y = z.z = z.w = 0.f;
    float4* o4 = reinterpret_cast<float4*>(dummy_out) + base;
    #pragma unroll 8
    for (int i = 0; i < 32; ++i)
        o4[(size_t)i * (NFILLB * 256)] = z;
}

// ---------- D2: compute (R22 verbatim) over CLUSTER-SORTED token list ----------
// Tokens in a block share (mostly) one target cluster -> the block's member
// gathers hit the same 96 KB row-set in L1/L2 instead of streaming ~400 MB.
// Per-token results are independent of processing order -> deterministic.
__global__ __launch_bounds__(512, 2) void hs_compute(
    const float* __restrict__ hidden,
    const float* __restrict__ item_emb,
    const float* __restrict__ cluster_emb,
    const float* __restrict__ item_mask,
    const int*   __restrict__ targets,
    const int*   __restrict__ cluster_assign,
    const int*   __restrict__ cluster_idx,
    const int*   __restrict__ in_cluster_id,
    const int*   __restrict__ wsI,
    float* __restrict__ ws)
{
    const int cb   = blockIdx.x;           // 0..511
    const int tid  = threadIdx.x;
    const int t0   = cb * TPB;
    const int lane = tid & 63;
    const int wave = tid >> 6;             // 0..7
    const int wq   = wave & 1;             // token quad (slots wq*4..+3)
    const int wqt  = wave >> 1;            // 64-cluster quarter 0..3
    const int q    = lane >> 4;            // cluster subgroup 0..3
    const int r    = lane & 15;            // 16-lane D-split

    __shared__ float clog[TPB][NUM_CLUSTERS];   // 8 KB
    __shared__ float mlog[TPB][64];             // 2 KB

    const int* list = wsI + 257;            // cluster-sorted token ids

    // ---- cluster logits: wave covers 64 clusters x 4 (sorted) tokens ----
    const float4* h4 = reinterpret_cast<const float4*>(hidden);
    int tok[4];
    #pragma unroll
    for (int j = 0; j < 4; ++j) tok[j] = list[t0 + wq * 4 + j];
    float4 hf[4][6];
    #pragma unroll
    for (int j = 0; j < 4; ++j)
        #pragma unroll
        for (int i = 0; i < 6; ++i)
            hf[j][i] = h4[(size_t)tok[j] * D4 + i * 16 + r];

    const float4* ce4 = reinterpret_cast<const float4*>(cluster_emb);
    #pragma unroll 2
    for (int it = 0; it < 16; ++it) {
        const int c = wqt * 64 + it * 4 + q;
        float4 ce[6];
        #pragma unroll
        for (int i = 0; i < 6; ++i) ce[i] = ce4[(size_t)c * D4 + i * 16 + r];
        float a0 = 0.f, a1 = 0.f, a2 = 0.f, a3 = 0.f;
        #pragma unroll
        for (int i = 0; i < 6; ++i) {
            a0 += dot4(ce[i], hf[0][i]);
            a1 += dot4(ce[i], hf[1][i]);
            a2 += dot4(ce[i], hf[2][i]);
            a3 += dot4(ce[i], hf[3][i]);
        }
        // fold 4 accumulators over 16 lanes: 5 shuffles total
        const bool hi8 = (r & 8) != 0;
        float u  = hi8 ? a1 : a0;
        float uS = hi8 ? a0 : a1;
        u += __shfl_xor(uS, 8);
        float w  = hi8 ? a3 : a2;
        float wS = hi8 ? a2 : a3;
        w += __shfl_xor(wS, 8);
        const bool hi4 = (r & 4) != 0;
        float zv = hi4 ? w : u;
        float zS = hi4 ? u : w;
        zv += __shfl_xor(zS, 4);
        zv += __shfl_xor(zv, 2);
        zv += __shfl_xor(zv, 1);
        if ((r & 3) == 0) {
            const int m = (r >> 2) & 3;               // class -> slot {0,2,1,3}
            const int tokj = (m == 1) ? 2 : (m == 2) ? 1 : m;
            clog[wq * 4 + tokj][c] = zv;
        }
    }
    __syncthreads();   // four quarter-waves fill each slot's clog row

    // ---- per wave: finish ONE (sorted) token ----
    const int r8 = lane & 7;
    const int g8 = lane >> 3;
    const float4* ie4 = reinterpret_cast<const float4*>(item_emb);

    const int t  = wave;                   // local slot
    const int gt = list[t0 + t];           // real token id
    const int tgt  = targets[gt];
    const int tc   = cluster_assign[tgt];
    const int tpos = in_cluster_id[tgt];
    const float msk = item_mask[gt];

    // cluster softmax + argmax (first-index tiebreak)
    const float v0 = clog[t][lane];
    const float v1 = clog[t][lane + 64];
    const float v2 = clog[t][lane + 128];
    const float v3 = clog[t][lane + 192];
    float bv = v0; int bi = lane;
    if (v1 > bv) { bv = v1; bi = lane + 64;  }
    if (v2 > bv) { bv = v2; bi = lane + 128; }
    if (v3 > bv) { bv = v3; bi = lane + 192; }
    #pragma unroll
    for (int m = 32; m > 0; m >>= 1) {
        const float ov = __shfl_xor(bv, m);
        const int   oi = __shfl_xor(bi, m);
        if (ov > bv || (ov == bv && oi < bi)) { bv = ov; bi = oi; }
    }
    float e = expf(v0 - bv) + expf(v1 - bv) + expf(v2 - bv) + expf(v3 - bv);
    #pragma unroll
    for (int m = 32; m > 0; m >>= 1) e += __shfl_xor(e, m);
    const float lse = bv + logf(e);
    const float tlpc = clog[t][tc] - lse;

    // ---- member: 8-lane groups; block-mates share tc -> L1/L2 hits ----
    float4 hme[12];
    #pragma unroll
    for (int i = 0; i < 12; ++i)
        hme[i] = h4[(size_t)gt * D4 + i * 8 + r8];
    const int* crow = cluster_idx + (size_t)tc * MCS;
    #pragma unroll 2
    for (int it = 0; it < 8; ++it) {
        const int id = crow[it * 8 + g8];   // always >= 0 for slot < 64
        const float4* ir = ie4 + (size_t)id * D4;
        float pa = 0.f;
        #pragma unroll
        for (int i = 0; i < 12; ++i) pa += dot4(ir[i * 8 + r8], hme[i]);
        pa += __shfl_xor(pa, 1);
        pa += __shfl_xor(pa, 2);
        pa += __shfl_xor(pa, 4);
        if (r8 == 0) mlog[t][it * 8 + g8] = pa;
    }
    // wave-local softmax over 64 slots (exact: slots 64..127 are masked)
    const float w0 = mlog[t][lane];
    float mx = w0;
    #pragma unroll
    for (int m = 32; m > 0; m >>= 1) mx = fmaxf(mx, __shfl_xor(mx, m));
    float e2 = expf(w0 - mx);
    #pragma unroll
    for (int m = 32; m > 0; m >>= 1) e2 += __shfl_xor(e2, m);
    const float tlpi = mlog[t][tpos] - (mx + logf(e2));

    if (lane == 0) {
        ws[NTOK + gt]     = msk;
        ws[2 * NTOK + gt] = tlpc;
        ws[3 * NTOK + gt] = tlpi;
        ws[4 * NTOK + gt] = (bi == tc) ? 1.f : 0.f;
    }
}

// ---------- D3: deterministic final reduction ----------
__global__ __launch_bounds__(1024) void hs_final(
    const float* __restrict__ ws, float* __restrict__ out)
{
    __shared__ double red[5][1024];
    const int tid = threadIdx.x;
    double a0 = 0, a1 = 0, a2 = 0, a3 = 0, a4 = 0;
    for (int i = tid; i < NTOK; i += 1024) {
        const float msk  = ws[NTOK + i];
        const float tlpc = ws[2 * NTOK + i];
        const float tlpi = ws[3 * NTOK + i];
        a0 += (double)(-(tlpc + tlpi) * msk);
        a1 += (double)msk;
        a2 += (double)tlpc;
        a3 += (double)tlpi;
        a4 += (double)ws[4 * NTOK + i];
    }
    red[0][tid] = a0; red[1][tid] = a1; red[2][tid] = a2;
    red[3][tid] = a3; red[4][tid] = a4;
    __syncthreads();
    for (int s2 = 512; s2 > 0; s2 >>= 1) {
        if (tid < s2) {
            red[0][tid] += red[0][tid + s2];
            red[1][tid] += red[1][tid + s2];
            red[2][tid] += red[2][tid + s2];
            red[3][tid] += red[3][tid + s2];
            red[4][tid] += red[4][tid + s2];
        }
        __syncthreads();
    }
    if (tid == 0) {
        out[0] = (float)(red[0][0] / (red[1][0] + 1e-8));
        out[1] = (float)(-red[2][0] / (double)NTOK);
        out[2] = (float)(-red[3][0] / (double)NTOK);
        out[3] = (float)(red[4][0] / (double)NTOK);
    }
}

extern "C" void kernel_launch(void* const* d_in, const int* in_sizes, int n_in,
                              void* d_out, int out_size, void* d_ws, size_t ws_size,
                              hipStream_t stream) {
    const float* hidden         = (const float*)d_in[0];
    const float* item_emb       = (const float*)d_in[1];
    const float* cluster_emb    = (const float*)d_in[2];
    const float* item_mask      = (const float*)d_in[3];
    const int*   targets        = (const int*)d_in[4];
    const int*   cluster_assign = (const int*)d_in[5];
    const int*   cluster_idx    = (const int*)d_in[6];
    const int*   in_cluster_id  = (const int*)d_in[7];

    float* out = (float*)d_out;
    float* ws  = (float*)d_ws;
    int*   wsI = (int*)(ws + 5 * NTOK);

    const size_t dummy_elems = (size_t)NTOK * NUM_ITEMS; // 67,108,864 zeros

    hs_fill_meta<<<NFILLB + 1, 256, 0, stream>>>(
        targets, cluster_assign, out, wsI);
    hs_compute<<<NCB, 512, 0, stream>>>(
        hidden, item_emb, cluster_emb, item_mask, targets,
        cluster_assign, cluster_idx, in_cluster_id, wsI, ws);
    hs_final<<<1, 1024, 0, stream>>>(ws, out + dummy_elems);
}